// Round 21
// baseline (243.893 us; speedup 1.0000x reference)
//
#include <hip/hip_runtime.h>
#include <math.h>

#define T_TRI 20000
#define KNN_K 20
#define H     128

// ---------------- workspace layout (bytes) ----------------
#define WS_GEO    0                       // 960KB (original-space geo)
#define WS_BQ     (1u<<20)                // 320KB
#define WS_NBR    (2u<<20)                // 1.6MB (sorted-space neighbor lists)
#define WS_RS     (4u<<20)                // 512B
#define WS_MT     ((4u<<20)+4096)         // MTg: 2*16384 f32 = 128KB (folded GEMMs)
#define WS_WV     ((4u<<20)+4096+(256u<<10)) // v0,v1,wf2,cst: 385 f32
#define WS_MM     (5u<<20)                // 64B
#define WS_CSTART ((5u<<20)+64)           // 4097 u32
#define WS_CPTR   ((5u<<20)+(32u<<10))    // 4096 u32
#define WS_HIST   ((5u<<20)+(64u<<10))    // 4096 u32
#define WS_CID    ((5u<<20)+(128u<<10))   // 20000 i32
#define WS_CSORT  ((5u<<20)+(256u<<10))   // 20000 i32
#define WS_OID    ((5u<<20)+(384u<<10))   // 20000 i32
#define WS_BQS    ((5u<<20)+(512u<<10))   // 320KB
#define WS_WA     ((5u<<20)+(840u<<10))   // 3*9*128 f32
#define WS_PS     (6u<<20)                // 80KB (probs_s)
#define WS_GEOS   (7u<<20)                // 960KB (sorted-space geo)
#define WS_ZB     (9u<<20)                // Z ping buffer
#define WS_ZA     (20u<<20)               // Z pong buffer

__device__ __forceinline__ float readlane_f(float v, int l) {
    return __uint_as_float(__builtin_amdgcn_readlane(__float_as_uint(v), l));
}
// order-preserving float<->uint (for atomicMin/Max on floats)
__device__ __forceinline__ unsigned encf(float f) {
    unsigned u = __float_as_uint(f);
    return (u & 0x80000000u) ? ~u : (u | 0x80000000u);
}
__device__ __forceinline__ float decf(unsigned e) {
    unsigned u = (e & 0x80000000u) ? (e & 0x7FFFFFFFu) : ~e;
    return __uint_as_float(u);
}
// m204 bijective XCD swizzle (R15/R16: aligns producer/consumer row-chunks).
__device__ __forceinline__ int xcd_swz(int bid, int nwg) {
    int q = nwg >> 3, rm = nwg & 7;
    int x = bid & 7, idx = bid >> 3;
    return (x < rm) ? x*(q+1) + idx : rm*(q+1) + (x-rm)*q + idx;
}

// ---------------- setup: hist/mm init + prep scalars + folded matrices (1 launch) ----------------
__global__ void setup_kernel(const float* __restrict__ W10, const float* __restrict__ W11,
                             const float* __restrict__ W12,
                             const float* __restrict__ W20, const float* __restrict__ W21,
                             const float* __restrict__ b20, const float* __restrict__ b21,
                             const float* __restrict__ b22, const float* __restrict__ W22,
                             const float* __restrict__ Wf, const float* __restrict__ bf,
                             unsigned* __restrict__ hist, unsigned* __restrict__ mm,
                             float* __restrict__ rs, float* __restrict__ WA,
                             float* __restrict__ WV, float* __restrict__ MTg) {
    int bx = blockIdx.x, by = blockIdx.y, tid = threadIdx.x;   // 128 threads
    if (bx < 128) {
        // MTg[m][f][c] interleaved: M_m = W1b_{m+1} @ W2_m
        int f = bx, c = tid, m = by;
        const float* W1 = m ? W12 : W11;
        const float* W2 = m ? W21 : W20;
        float acc = 0.f;
        for (int k = 0; k < 128; ++k)
            acc = fmaf(W1[f*137 + 9 + k], W2[k*128 + c], acc);
        MTg[m*16384 + (c>>2)*512 + f*4 + (c&3)] = acc;
    } else if (bx == 128) {
        if (by != 0) return;
        int f = tid;
        float s = 0.f;
        for (int c = 0; c < H; ++c) s += W10[f*137 + 9 + c];
        rs[f] = s;
#pragma unroll
        for (int c = 0; c < 9; ++c) {
            WA[0*1152 + c*128 + f] = W10[f*137 + c];
            WA[1*1152 + c*128 + f] = W11[f*137 + c];
            WA[2*1152 + c*128 + f] = W12[f*137 + c];
        }
        float v0 = 0.f, v1 = 0.f, w2 = 0.f;
        for (int k = 0; k < 128; ++k) {
            v0 = fmaf(W11[f*137 + 9 + k], b20[k], v0);
            v1 = fmaf(W12[f*137 + 9 + k], b21[k], v1);
            w2 = fmaf(Wf[k], W22[k*128 + f], w2);
        }
        WV[f]       = (float)KNN_K * v0;
        WV[128 + f] = (float)KNN_K * v1;
        WV[256 + f] = w2;
        if (f == 0) {
            float cacc = 0.f;
            for (int k = 0; k < 128; ++k) cacc = fmaf(Wf[k], b22[k], cacc);
            WV[384] = (float)KNN_K * cacc + bf[0];
        }
    } else {
#pragma unroll
        for (int i = 0; i < 16; ++i) hist[by*2048 + tid*16 + i] = 0u;
        if (by == 0 && tid < 3) mm[tid] = 0xFFFFFFFFu;
        if (by == 0 && tid >= 3 && tid < 6) mm[tid] = 0u;
    }
}

// ---------------- geometry (+ bary AABB via wave-reduced atomics) ----------------
__global__ void geom_kernel(const float* __restrict__ pts, const int* __restrict__ tris,
                            float* __restrict__ geo, float4* __restrict__ bq,
                            unsigned* __restrict__ mm) {
    int t = blockIdx.x * blockDim.x + threadIdx.x;
    int lane = threadIdx.x & 63;
    bool act = (t < T_TRI);
    int tt = act ? t : 0;
    int i0 = tris[3*tt], i1 = tris[3*tt+1], i2 = tris[3*tt+2];
    float ax = pts[3*i0], ay = pts[3*i0+1], az = pts[3*i0+2];
    float bx = pts[3*i1], by = pts[3*i1+1], bz = pts[3*i1+2];
    float cx = pts[3*i2], cy = pts[3*i2+1], cz = pts[3*i2+2];
    float e0x = ax-bx, e0y = ay-by, e0z = az-bz;   // e_ij
    float e1x = ax-cx, e1y = ay-cy, e1z = az-cz;   // e_ik
    float e2x = bx-cx, e2y = by-cy, e2z = bz-cz;   // e_jk
    float mnx = fminf(fminf(e0x,e1x),e2x), mny = fminf(fminf(e0y,e1y),e2y), mnz = fminf(fminf(e0z,e1z),e2z);
    float mxx = fmaxf(fmaxf(e0x,e1x),e2x), mxy = fmaxf(fmaxf(e0y,e1y),e2y), mxz = fmaxf(fmaxf(e0z,e1z),e2z);
    float gx = (ax+bx+cx)*(1.0f/3.0f), gy = (ay+by+cy)*(1.0f/3.0f), gz = (az+bz+cz)*(1.0f/3.0f);
    float sq = (gx*gx + gy*gy) + gz*gz;
    if (act) {
        float* g = geo + (size_t)t*12;
        g[0]=mnx; g[1]=mny; g[2]=mnz; g[3]=mxx; g[4]=mxy; g[5]=mxz;
        g[6]=gx;  g[7]=gy;  g[8]=gz;  g[9]=0.f; g[10]=0.f; g[11]=0.f;
        bq[t] = make_float4(gx, gy, gz, sq);
    }
    unsigned n0 = act ? encf(gx) : 0xFFFFFFFFu;
    unsigned n1 = act ? encf(gy) : 0xFFFFFFFFu;
    unsigned n2 = act ? encf(gz) : 0xFFFFFFFFu;
    unsigned x0 = act ? encf(gx) : 0u;
    unsigned x1 = act ? encf(gy) : 0u;
    unsigned x2 = act ? encf(gz) : 0u;
#pragma unroll
    for (int off = 32; off >= 1; off >>= 1) {
        n0 = min(n0, (unsigned)__shfl_xor((int)n0, off));
        n1 = min(n1, (unsigned)__shfl_xor((int)n1, off));
        n2 = min(n2, (unsigned)__shfl_xor((int)n2, off));
        x0 = max(x0, (unsigned)__shfl_xor((int)x0, off));
        x1 = max(x1, (unsigned)__shfl_xor((int)x1, off));
        x2 = max(x2, (unsigned)__shfl_xor((int)x2, off));
    }
    if (lane == 0) {
        atomicMin(&mm[0], n0); atomicMin(&mm[1], n1); atomicMin(&mm[2], n2);
        atomicMax(&mm[3], x0); atomicMax(&mm[4], x1); atomicMax(&mm[5], x2);
    }
}

// ---------------- cell assignment + histogram ----------------
__global__ void cellhist_kernel(const float4* __restrict__ bq, const unsigned* __restrict__ mm,
                                int* __restrict__ cellid, unsigned* __restrict__ hist) {
    int t = blockIdx.x * 256 + threadIdx.x;
    if (t >= T_TRI) return;
    float mnx = decf(mm[0]), mny = decf(mm[1]), mnz = decf(mm[2]);
    float mxx = decf(mm[3]), mxy = decf(mm[4]), mxz = decf(mm[5]);
    float ihx = 16.f / fmaxf(mxx-mnx, 1e-30f);
    float ihy = 16.f / fmaxf(mxy-mny, 1e-30f);
    float ihz = 16.f / fmaxf(mxz-mnz, 1e-30f);
    float4 b = bq[t];
    int ix = min(15, max(0, (int)((b.x-mnx)*ihx)));
    int iy = min(15, max(0, (int)((b.y-mny)*ihy)));
    int iz = min(15, max(0, (int)((b.z-mnz)*ihz)));
    int c = (ix<<8) | (iy<<4) | iz;
    cellid[t] = c;
    atomicAdd(&hist[c], 1u);
}

// ---------------- exclusive prefix over 4096 cells (1 block) ----------------
__global__ __launch_bounds__(1024) void prefix_kernel(const unsigned* __restrict__ hist,
                                                      unsigned* __restrict__ cellstart,
                                                      unsigned* __restrict__ cellptr) {
    __shared__ unsigned sbuf[1024];
    int tid = threadIdx.x;
    uint4 v = ((const uint4*)hist)[tid];
    unsigned mysum = v.x + v.y + v.z + v.w;
    sbuf[tid] = mysum;
    __syncthreads();
    for (int off = 1; off < 1024; off <<= 1) {
        unsigned add = (tid >= off) ? sbuf[tid - off] : 0u;
        __syncthreads();
        sbuf[tid] += add;
        __syncthreads();
    }
    unsigned excl = sbuf[tid] - mysum;
    unsigned p0 = excl, p1 = p0 + v.x, p2 = p1 + v.y, p3 = p2 + v.z;
    cellstart[4*tid+0] = p0; cellstart[4*tid+1] = p1;
    cellstart[4*tid+2] = p2; cellstart[4*tid+3] = p3;
    cellptr[4*tid+0] = p0; cellptr[4*tid+1] = p1;
    cellptr[4*tid+2] = p2; cellptr[4*tid+3] = p3;
    if (tid == 1023) cellstart[4096] = p3 + v.w;
}

// ---------------- scatter into cell-sorted order (+ relabeled geo/probs) ----------------
__global__ void scatter_kernel(const float4* __restrict__ bq, const int* __restrict__ cellid,
                               const float* __restrict__ geo, const float* __restrict__ probs,
                               unsigned* __restrict__ cellptr, float4* __restrict__ bqs,
                               int* __restrict__ oid, int* __restrict__ csort,
                               float* __restrict__ geo_s, float* __restrict__ probs_s) {
    int t = blockIdx.x * 256 + threadIdx.x;
    if (t >= T_TRI) return;
    int c = cellid[t];
    unsigned p = atomicAdd(&cellptr[c], 1u);
    bqs[p] = bq[t];
    oid[p]  = t;
    csort[p] = c;
    const float4* g4 = (const float4*)geo;
    float4* g4s = (float4*)geo_s;
    g4s[(size_t)p*3+0] = g4[(size_t)t*3+0];
    g4s[(size_t)p*3+1] = g4[(size_t)t*3+1];
    g4s[(size_t)p*3+2] = g4[(size_t)t*3+2];
    probs_s[p] = probs[t];
}

// ---------------- grid KNN — R18/R20 kernel + strided block->row load balance ----------------
// Sorted order clusters dense (Gaussian-core) rows into a contiguous block
// range -> CU-level imbalance (R20: Occ 44%, VALUBusy 52%, FETCH tiny).
// Bijective remap rp=(b%40)*125+b/40 (5000=40x125) gives concurrent blocks a
// uniform density mix; rows within a block stay adjacent (shared L2 lines).
// Pure scheduling change — candidate set and selection math untouched.
__global__ __launch_bounds__(256) void knn_grid_kernel(const float4* __restrict__ bqs,
        const int* __restrict__ oid, const int* __restrict__ csort,
        const unsigned* __restrict__ cellstart, const unsigned* __restrict__ mm,
        int* __restrict__ nbr) {
    int wave = threadIdx.x >> 6, lane = threadIdx.x & 63;
    int rp = (blockIdx.x % 40) * 125 + blockIdx.x / 40;   // bijective over [0,5000)
    int r = rp * 4 + wave;
    float4 q = bqs[r];
    int myc = csort[r];
    int cx = (myc>>8)&15, cy = (myc>>4)&15, cz = myc&15;
    float mnx = decf(mm[0]), mny = decf(mm[1]), mnz = decf(mm[2]);
    float hx = (decf(mm[3]) - mnx) * (1.f/16.f);
    float hy = (decf(mm[4]) - mny) * (1.f/16.f);
    float hz = (decf(mm[5]) - mnz) * (1.f/16.f);
    float hmin = fminf(hx, fminf(hy, hz));

    float rd = INFINITY;
    int   ri = 0x7FF00000 | lane;     // distinct sentinels (orig-idx key)
    int   rk = lane;                  // sorted-idx payload
    float th = INFINITY;
    int   mi = 0x7FFFFFFF;

#define SCAN_RANGE(RS, RE)                                                          \
    for (unsigned base = (RS); base < (RE); base += 64u) {                          \
        unsigned k = base + (unsigned)lane;                                         \
        bool kv = (k < (RE));                                                       \
        float4 c4 = kv ? bqs[k] : make_float4(INFINITY,INFINITY,INFINITY,INFINITY); \
        int ov = kv ? oid[k] : 0x7FFFFFFF;                                          \
        float dot = fmaf(q.z, c4.z, fmaf(q.y, c4.y, q.x*c4.x));                     \
        float d = (q.w + c4.w) - 2.0f*dot;                                          \
        unsigned long long bal = __ballot(kv && (d <= th));                         \
        while (bal) {                                                               \
            int src = __ffsll(bal) - 1; bal &= bal - 1;                             \
            float dc = readlane_f(d, src);                                          \
            int   jc = __builtin_amdgcn_readlane(ov, src);                          \
            int   kc = (int)base + src;                                             \
            if ((dc < th) || (dc == th && jc < mi)) {                               \
                bool less = (rd < dc) || (rd == dc && ri < jc);                     \
                int pos = __popcll(__ballot(less) & 0x1FFFFFull);                   \
                float sd = __shfl_up(rd, 1);                                        \
                int   si = __shfl_up(ri, 1);                                        \
                int   sk = __shfl_up(rk, 1);                                        \
                if (lane < 21) {                                                    \
                    if (lane == pos)      { rd = dc; ri = jc; rk = kc; }            \
                    else if (lane > pos)  { rd = sd; ri = si; rk = sk; }            \
                }                                                                   \
                th = readlane_f(rd, 20);                                            \
                mi = __builtin_amdgcn_readlane(ri, 20);                             \
            }                                                                       \
        }                                                                           \
    }

#define CELL_BOUND_OK(EX, EY, EZ)                                                   \
    ({  float cl0 = fmaf((float)(EX), hx, mnx);                                     \
        float cm0 = fmaf((float)(EY), hy, mny);                                     \
        float cn0 = fmaf((float)(EZ), hz, mnz);                                     \
        float ddx = fmaxf(fmaxf(cl0 - q.x, q.x - (cl0 + hx)), 0.f);                 \
        float ddy = fmaxf(fmaxf(cm0 - q.y, q.y - (cm0 + hy)), 0.f);                 \
        float ddz = fmaxf(fmaxf(cn0 - q.z, q.z - (cn0 + hz)), 0.f);                 \
        float bnd = fmaf(ddx, ddx, fmaf(ddy, ddy, ddz*ddz));                        \
        (bnd <= th + 1e-3f); })

    // ---- home cell: first batch via bitonic sort (warm-up elimination) ----
    {
        unsigned hs = cellstart[myc], he = cellstart[myc + 1];
        unsigned k64 = hs + (unsigned)lane;
        bool kv = (k64 < he);
        float4 c4 = kv ? bqs[k64] : make_float4(INFINITY,INFINITY,INFINITY,INFINITY);
        float dot = fmaf(q.z, c4.z, fmaf(q.y, c4.y, q.x*c4.x));
        float d = (q.w + c4.w) - 2.0f*dot;
        int   jx = kv ? oid[k64] : (0x7FF00000 | lane);
        int   kc = kv ? (int)k64 : 0;
        if (!kv) d = INFINITY;          // kill NaN/INF garbage: sort needs clean keys
#pragma unroll
        for (int kk = 2; kk <= 64; kk <<= 1) {
#pragma unroll
            for (int jj = kk >> 1; jj >= 1; jj >>= 1) {
                float od = __shfl_xor(d, jj);
                int   oj = __shfl_xor(jx, jj);
                int   ok = __shfl_xor(kc, jj);
                bool up    = ((lane & kk) == 0);
                bool lower = ((lane & jj) == 0);
                bool less  = (d < od) || (d == od && jx < oj);
                bool keep  = ((lower == up) ? less : !less);
                d = keep ? d : od; jx = keep ? jx : oj; kc = keep ? kc : ok;
            }
        }
        rd = d; ri = jx; rk = kc;       // lane l = rank-l (junk for l>20, harmless)
        th = readlane_f(rd, 20);
        mi = __builtin_amdgcn_readlane(ri, 20);
        if (hs + 64u < he) { SCAN_RANGE(hs + 64u, he) }
    }

    for (int w = 1; w <= 15; ++w) {
        if (w == 1) {
            int i = lane;
            bool val = (i < 27) && (i != 13);
            int ii = (i < 27) ? i : 0;
            int dz = ii % 3 - 1, dy = (ii / 3) % 3 - 1, dx = ii / 9 - 1;
            int ex = cx + dx, ey = cy + dy, ez = cz + dz;
            val = val && ex >= 0 && ex < 16 && ey >= 0 && ey < 16 && ez >= 0 && ez < 16;
            int cell = (ex<<8) | (ey<<4) | ez;
            unsigned cs = 0u, ce = 0u;
            if (val) { cs = cellstart[cell]; ce = cellstart[cell+1]; }
            val = val && (cs < ce);
            if (val) val = CELL_BOUND_OK(ex, ey, ez);
            unsigned long long cm = __ballot(val);
            while (cm) {
                int cl = __ffsll(cm) - 1; cm &= cm - 1;
                unsigned s0 = (unsigned)__builtin_amdgcn_readlane((int)cs, cl);
                unsigned e0 = (unsigned)__builtin_amdgcn_readlane((int)ce, cl);
                SCAN_RANGE(s0, e0)
            }
        } else {
            int W = 2*w + 1, W2 = W*W, tot = W*W2;
            for (int b0 = 0; b0 < tot; b0 += 64) {
                int i = b0 + lane;
                bool val = (i < tot);
                int ii = val ? i : 0;
                int dz = ii % W - w, dy = (ii / W) % W - w, dx = ii / W2 - w;
                int cheb = max(abs(dx), max(abs(dy), abs(dz)));
                val = val && (cheb == w);
                int ex = cx + dx, ey = cy + dy, ez = cz + dz;
                val = val && ex >= 0 && ex < 16 && ey >= 0 && ey < 16 && ez >= 0 && ez < 16;
                int cell = (ex<<8) | (ey<<4) | ez;
                unsigned cs = 0u, ce = 0u;
                if (val) { cs = cellstart[cell]; ce = cellstart[cell+1]; }
                val = val && (cs < ce);
                if (val) val = CELL_BOUND_OK(ex, ey, ez);
                unsigned long long cm = __ballot(val);
                while (cm) {
                    int cl = __ffsll(cm) - 1; cm &= cm - 1;
                    unsigned s0 = (unsigned)__builtin_amdgcn_readlane((int)cs, cl);
                    unsigned e0 = (unsigned)__builtin_amdgcn_readlane((int)ce, cl);
                    SCAN_RANGE(s0, e0)
                }
            }
        }
        bool covered = (cx-w <= 0) && (cx+w >= 15) && (cy-w <= 0) && (cy+w >= 15)
                    && (cz-w <= 0) && (cz+w >= 15);
        if (covered) break;
        float bd = (float)w * hmin - 1e-3f;
        if (bd > 0.f && th < bd*bd) break;
    }
#undef CELL_BOUND_OK
#undef SCAN_RANGE
    if (lane >= 1 && lane < 21) nbr[r*KNN_K + lane - 1] = rk;
}

// ---------------- layer-0 Z ----------------
__global__ void y0_kernel(const float* __restrict__ ps, const float* __restrict__ rs,
                          const float* __restrict__ WA0, const float* __restrict__ geo_s,
                          float* __restrict__ Z) {
    int bid = xcd_swz(blockIdx.x, gridDim.x);
    int tid = bid * 256 + threadIdx.x;   // over T*H
    int t = tid >> 7, f = tid & 127;
    float acc = ps[t] * rs[f];
#pragma unroll
    for (int c = 0; c < 9; ++c)
        acc = fmaf(WA0[c*128 + f], geo_s[(size_t)t*12 + c], acc);
    Z[tid] = acc;
}

// ---------------- mid-layer fused: 8 rows / 512-thread block ----------------
__global__ __launch_bounds__(512) void ef_mid_kernel(const float* __restrict__ Z,
                            const int* __restrict__ nbr, const float* __restrict__ b1,
                            const float* __restrict__ MTg, const float* __restrict__ v,
                            const float* __restrict__ WAn, const float* __restrict__ geo_s,
                            float* __restrict__ Znext) {
    __shared__ float Srow[8][128];
    int wave = threadIdx.x >> 6, lane = threadIdx.x & 63;
    int t0b = xcd_swz(blockIdx.x, gridDim.x) * 8;
    {
        int t = t0b + wave;
        float zsLo = Z[(size_t)t*H + lane]      + b1[lane];
        float zsHi = Z[(size_t)t*H + 64 + lane] + b1[64 + lane];
        float accLo = 0.f, accHi = 0.f;
#pragma unroll
        for (int e = 0; e < KNN_K; ++e) {
            int tg = nbr[t*KNN_K + e];
            accLo += fmaxf(zsLo - Z[(size_t)tg*H + lane],      0.f);
            accHi += fmaxf(zsHi - Z[(size_t)tg*H + 64 + lane], 0.f);
        }
        Srow[wave][lane]    = accLo;
        Srow[wave][64+lane] = accHi;
    }
    __syncthreads();
    int f = threadIdx.x & 127, grp = threadIdx.x >> 7;   // 4 groups x 2 rows
    float a0 = v[f], a1 = v[f];
    const int r0_ = grp * 2;
#pragma unroll
    for (int c4 = 0; c4 < 32; ++c4) {
        float4 w = *(const float4*)&MTg[c4*512 + f*4];
        float4 v0 = ((const float4*)Srow[r0_+0])[c4];
        float4 v1 = ((const float4*)Srow[r0_+1])[c4];
        a0 = fmaf(w.x, v0.x, a0); a0 = fmaf(w.y, v0.y, a0);
        a0 = fmaf(w.z, v0.z, a0); a0 = fmaf(w.w, v0.w, a0);
        a1 = fmaf(w.x, v1.x, a1); a1 = fmaf(w.y, v1.y, a1);
        a1 = fmaf(w.z, v1.z, a1); a1 = fmaf(w.w, v1.w, a1);
    }
#pragma unroll
    for (int c = 0; c < 9; ++c) {
        float w = WAn[c*128 + f];
        a0 = fmaf(w, geo_s[(size_t)(t0b + r0_ + 0)*12 + c], a0);
        a1 = fmaf(w, geo_s[(size_t)(t0b + r0_ + 1)*12 + c], a1);
    }
    Znext[(size_t)(t0b+r0_+0)*H + f] = a0;
    Znext[(size_t)(t0b+r0_+1)*H + f] = a1;
}

// ---------------- last-layer fused: edge -> dot(S, wf2) + cst -> sigmoid ----------------
__global__ __launch_bounds__(256) void ef_head_kernel(const float* __restrict__ Z,
                            const int* __restrict__ nbr, const float* __restrict__ b1,
                            const float* __restrict__ WV, float* __restrict__ out,
                            const int* __restrict__ oid) {
    int wave = threadIdx.x >> 6, lane = threadIdx.x & 63;
    int t = xcd_swz(blockIdx.x, gridDim.x) * 4 + wave;
    float zsLo = Z[(size_t)t*H + lane]      + b1[lane];
    float zsHi = Z[(size_t)t*H + 64 + lane] + b1[64 + lane];
    float accLo = 0.f, accHi = 0.f;
#pragma unroll
    for (int e = 0; e < KNN_K; ++e) {
        int tg = nbr[t*KNN_K + e];
        accLo += fmaxf(zsLo - Z[(size_t)tg*H + lane],      0.f);
        accHi += fmaxf(zsHi - Z[(size_t)tg*H + 64 + lane], 0.f);
    }
    float p = fmaf(accLo, WV[256 + lane], accHi * WV[256 + 64 + lane]);
#pragma unroll
    for (int off = 32; off >= 1; off >>= 1) p += __shfl_xor(p, off);
    if (lane == 0) {
        float z = p + WV[384];
        out[oid[t]] = 1.0f / (1.0f + expf(-z));
    }
}

extern "C" void kernel_launch(void* const* d_in, const int* in_sizes, int n_in,
                              void* d_out, int out_size, void* d_ws, size_t ws_size,
                              hipStream_t stream) {
    (void)in_sizes; (void)n_in; (void)out_size; (void)ws_size;
    const float* pts   = (const float*)d_in[0];
    const int*   tris  = (const int*)d_in[1];
    const float* probs = (const float*)d_in[2];
    const float* W1[3] = {(const float*)d_in[3],  (const float*)d_in[7],  (const float*)d_in[11]};
    const float* b1[3] = {(const float*)d_in[4],  (const float*)d_in[8],  (const float*)d_in[12]};
    const float* W2[3] = {(const float*)d_in[5],  (const float*)d_in[9],  (const float*)d_in[13]};
    const float* b2[3] = {(const float*)d_in[6],  (const float*)d_in[10], (const float*)d_in[14]};
    const float* Wf = (const float*)d_in[15];
    const float* bf = (const float*)d_in[16];
    float* out = (float*)d_out;

    char* ws = (char*)d_ws;
    float*    geo  = (float*)(ws + WS_GEO);
    float4*   bq   = (float4*)(ws + WS_BQ);
    int*      nbr  = (int*)(ws + WS_NBR);
    float*    rs   = (float*)(ws + WS_RS);
    float*    MTg  = (float*)(ws + WS_MT);
    float*    WV   = (float*)(ws + WS_WV);
    unsigned* mm   = (unsigned*)(ws + WS_MM);
    unsigned* cst  = (unsigned*)(ws + WS_CSTART);
    unsigned* cptr = (unsigned*)(ws + WS_CPTR);
    unsigned* hist = (unsigned*)(ws + WS_HIST);
    int*      cid  = (int*)(ws + WS_CID);
    int*      cso  = (int*)(ws + WS_CSORT);
    int*      oid  = (int*)(ws + WS_OID);
    float4*   bqs  = (float4*)(ws + WS_BQS);
    float*    WA   = (float*)(ws + WS_WA);
    float*    ps   = (float*)(ws + WS_PS);
    float*    geos = (float*)(ws + WS_GEOS);
    float*    Za   = (float*)(ws + WS_ZA);
    float*    Zb   = (float*)(ws + WS_ZB);

    setup_kernel<<<dim3(130,2), 128, 0, stream>>>(W1[0], W1[1], W1[2], W2[0], W2[1],
                                                  b2[0], b2[1], b2[2], W2[2], Wf, bf,
                                                  hist, mm, rs, WA, WV, MTg);
    geom_kernel<<<(T_TRI+255)/256, 256, 0, stream>>>(pts, tris, geo, bq, mm);
    cellhist_kernel<<<(T_TRI+255)/256, 256, 0, stream>>>(bq, mm, cid, hist);
    prefix_kernel<<<1, 1024, 0, stream>>>(hist, cst, cptr);
    scatter_kernel<<<(T_TRI+255)/256, 256, 0, stream>>>(bq, cid, geo, probs, cptr, bqs, oid, cso, geos, ps);
    knn_grid_kernel<<<T_TRI/4, 256, 0, stream>>>(bqs, oid, cso, cst, mm, nbr);
    y0_kernel<<<(T_TRI*H)/256, 256, 0, stream>>>(ps, rs, WA, geos, Za);
    ef_mid_kernel<<<T_TRI/8, 512, 0, stream>>>(Za, nbr, b1[0], MTg,         WV,       WA + 1*1152, geos, Zb);
    ef_mid_kernel<<<T_TRI/8, 512, 0, stream>>>(Zb, nbr, b1[1], MTg + 16384, WV + 128, WA + 2*1152, geos, Za);
    ef_head_kernel<<<T_TRI/4, 256, 0, stream>>>(Za, nbr, b1[2], WV, out, oid);
}

// Round 22
// 241.579 us; speedup vs baseline: 1.0096x; 1.0096x over previous
//
#include <hip/hip_runtime.h>
#include <math.h>

#define T_TRI 20000
#define KNN_K 20
#define H     128

// ---------------- workspace layout (bytes) ----------------
#define WS_GEO    0                       // 960KB (original-space geo)
#define WS_BQ     (1u<<20)                // 320KB
#define WS_NBR    (2u<<20)                // 1.6MB (sorted-space neighbor lists)
#define WS_RS     (4u<<20)                // 512B
#define WS_MT     ((4u<<20)+4096)         // MTg: 2*16384 f32 = 128KB (folded GEMMs)
#define WS_WV     ((4u<<20)+4096+(256u<<10)) // v0,v1,wf2,cst: 385 f32
#define WS_MM     (5u<<20)                // 64B
#define WS_CSTART ((5u<<20)+64)           // 4097 u32
#define WS_CPTR   ((5u<<20)+(32u<<10))    // 4096 u32
#define WS_HIST   ((5u<<20)+(64u<<10))    // 4096 u32
#define WS_CID    ((5u<<20)+(128u<<10))   // 20000 i32
#define WS_CSORT  ((5u<<20)+(256u<<10))   // 20000 i32
#define WS_OID    ((5u<<20)+(384u<<10))   // 20000 i32
#define WS_BQS    ((5u<<20)+(512u<<10))   // 320KB
#define WS_WA     ((5u<<20)+(840u<<10))   // 3*9*128 f32
#define WS_PS     (6u<<20)                // 80KB (probs_s)
#define WS_GEOS   (7u<<20)                // 960KB (sorted-space geo)
#define WS_ZB     (9u<<20)                // Z ping buffer
#define WS_ZA     (20u<<20)               // Z pong buffer

__device__ __forceinline__ float readlane_f(float v, int l) {
    return __uint_as_float(__builtin_amdgcn_readlane(__float_as_uint(v), l));
}
// order-preserving float<->uint (for atomicMin/Max on floats)
__device__ __forceinline__ unsigned encf(float f) {
    unsigned u = __float_as_uint(f);
    return (u & 0x80000000u) ? ~u : (u | 0x80000000u);
}
__device__ __forceinline__ float decf(unsigned e) {
    unsigned u = (e & 0x80000000u) ? (e & 0x7FFFFFFFu) : ~e;
    return __uint_as_float(u);
}
// m204 bijective XCD swizzle (R15/R16: aligns producer/consumer row-chunks).
__device__ __forceinline__ int xcd_swz(int bid, int nwg) {
    int q = nwg >> 3, rm = nwg & 7;
    int x = bid & 7, idx = bid >> 3;
    return (x < rm) ? x*(q+1) + idx : rm*(q+1) + (x-rm)*q + idx;
}

// ---------------- setup: hist/mm init + prep scalars + folded matrices (1 launch) ----------------
__global__ void setup_kernel(const float* __restrict__ W10, const float* __restrict__ W11,
                             const float* __restrict__ W12,
                             const float* __restrict__ W20, const float* __restrict__ W21,
                             const float* __restrict__ b20, const float* __restrict__ b21,
                             const float* __restrict__ b22, const float* __restrict__ W22,
                             const float* __restrict__ Wf, const float* __restrict__ bf,
                             unsigned* __restrict__ hist, unsigned* __restrict__ mm,
                             float* __restrict__ rs, float* __restrict__ WA,
                             float* __restrict__ WV, float* __restrict__ MTg) {
    int bx = blockIdx.x, by = blockIdx.y, tid = threadIdx.x;   // 128 threads
    if (bx < 128) {
        // MTg[m][f][c] interleaved: M_m = W1b_{m+1} @ W2_m
        int f = bx, c = tid, m = by;
        const float* W1 = m ? W12 : W11;
        const float* W2 = m ? W21 : W20;
        float acc = 0.f;
        for (int k = 0; k < 128; ++k)
            acc = fmaf(W1[f*137 + 9 + k], W2[k*128 + c], acc);
        MTg[m*16384 + (c>>2)*512 + f*4 + (c&3)] = acc;
    } else if (bx == 128) {
        if (by != 0) return;
        int f = tid;
        float s = 0.f;
        for (int c = 0; c < H; ++c) s += W10[f*137 + 9 + c];
        rs[f] = s;
#pragma unroll
        for (int c = 0; c < 9; ++c) {
            WA[0*1152 + c*128 + f] = W10[f*137 + c];
            WA[1*1152 + c*128 + f] = W11[f*137 + c];
            WA[2*1152 + c*128 + f] = W12[f*137 + c];
        }
        float v0 = 0.f, v1 = 0.f, w2 = 0.f;
        for (int k = 0; k < 128; ++k) {
            v0 = fmaf(W11[f*137 + 9 + k], b20[k], v0);
            v1 = fmaf(W12[f*137 + 9 + k], b21[k], v1);
            w2 = fmaf(Wf[k], W22[k*128 + f], w2);
        }
        WV[f]       = (float)KNN_K * v0;
        WV[128 + f] = (float)KNN_K * v1;
        WV[256 + f] = w2;
        if (f == 0) {
            float cacc = 0.f;
            for (int k = 0; k < 128; ++k) cacc = fmaf(Wf[k], b22[k], cacc);
            WV[384] = (float)KNN_K * cacc + bf[0];
        }
    } else {
#pragma unroll
        for (int i = 0; i < 16; ++i) hist[by*2048 + tid*16 + i] = 0u;
        if (by == 0 && tid < 3) mm[tid] = 0xFFFFFFFFu;
        if (by == 0 && tid >= 3 && tid < 6) mm[tid] = 0u;
    }
}

// ---------------- geometry (+ bary AABB via wave-reduced atomics) ----------------
__global__ void geom_kernel(const float* __restrict__ pts, const int* __restrict__ tris,
                            float* __restrict__ geo, float4* __restrict__ bq,
                            unsigned* __restrict__ mm) {
    int t = blockIdx.x * blockDim.x + threadIdx.x;
    int lane = threadIdx.x & 63;
    bool act = (t < T_TRI);
    int tt = act ? t : 0;
    int i0 = tris[3*tt], i1 = tris[3*tt+1], i2 = tris[3*tt+2];
    float ax = pts[3*i0], ay = pts[3*i0+1], az = pts[3*i0+2];
    float bx = pts[3*i1], by = pts[3*i1+1], bz = pts[3*i1+2];
    float cx = pts[3*i2], cy = pts[3*i2+1], cz = pts[3*i2+2];
    float e0x = ax-bx, e0y = ay-by, e0z = az-bz;   // e_ij
    float e1x = ax-cx, e1y = ay-cy, e1z = az-cz;   // e_ik
    float e2x = bx-cx, e2y = by-cy, e2z = bz-cz;   // e_jk
    float mnx = fminf(fminf(e0x,e1x),e2x), mny = fminf(fminf(e0y,e1y),e2y), mnz = fminf(fminf(e0z,e1z),e2z);
    float mxx = fmaxf(fmaxf(e0x,e1x),e2x), mxy = fmaxf(fmaxf(e0y,e1y),e2y), mxz = fmaxf(fmaxf(e0z,e1z),e2z);
    float gx = (ax+bx+cx)*(1.0f/3.0f), gy = (ay+by+cy)*(1.0f/3.0f), gz = (az+bz+cz)*(1.0f/3.0f);
    float sq = (gx*gx + gy*gy) + gz*gz;
    if (act) {
        float* g = geo + (size_t)t*12;
        g[0]=mnx; g[1]=mny; g[2]=mnz; g[3]=mxx; g[4]=mxy; g[5]=mxz;
        g[6]=gx;  g[7]=gy;  g[8]=gz;  g[9]=0.f; g[10]=0.f; g[11]=0.f;
        bq[t] = make_float4(gx, gy, gz, sq);
    }
    unsigned n0 = act ? encf(gx) : 0xFFFFFFFFu;
    unsigned n1 = act ? encf(gy) : 0xFFFFFFFFu;
    unsigned n2 = act ? encf(gz) : 0xFFFFFFFFu;
    unsigned x0 = act ? encf(gx) : 0u;
    unsigned x1 = act ? encf(gy) : 0u;
    unsigned x2 = act ? encf(gz) : 0u;
#pragma unroll
    for (int off = 32; off >= 1; off >>= 1) {
        n0 = min(n0, (unsigned)__shfl_xor((int)n0, off));
        n1 = min(n1, (unsigned)__shfl_xor((int)n1, off));
        n2 = min(n2, (unsigned)__shfl_xor((int)n2, off));
        x0 = max(x0, (unsigned)__shfl_xor((int)x0, off));
        x1 = max(x1, (unsigned)__shfl_xor((int)x1, off));
        x2 = max(x2, (unsigned)__shfl_xor((int)x2, off));
    }
    if (lane == 0) {
        atomicMin(&mm[0], n0); atomicMin(&mm[1], n1); atomicMin(&mm[2], n2);
        atomicMax(&mm[3], x0); atomicMax(&mm[4], x1); atomicMax(&mm[5], x2);
    }
}

// ---------------- cell assignment + histogram ----------------
__global__ void cellhist_kernel(const float4* __restrict__ bq, const unsigned* __restrict__ mm,
                                int* __restrict__ cellid, unsigned* __restrict__ hist) {
    int t = blockIdx.x * 256 + threadIdx.x;
    if (t >= T_TRI) return;
    float mnx = decf(mm[0]), mny = decf(mm[1]), mnz = decf(mm[2]);
    float mxx = decf(mm[3]), mxy = decf(mm[4]), mxz = decf(mm[5]);
    float ihx = 16.f / fmaxf(mxx-mnx, 1e-30f);
    float ihy = 16.f / fmaxf(mxy-mny, 1e-30f);
    float ihz = 16.f / fmaxf(mxz-mnz, 1e-30f);
    float4 b = bq[t];
    int ix = min(15, max(0, (int)((b.x-mnx)*ihx)));
    int iy = min(15, max(0, (int)((b.y-mny)*ihy)));
    int iz = min(15, max(0, (int)((b.z-mnz)*ihz)));
    int c = (ix<<8) | (iy<<4) | iz;
    cellid[t] = c;
    atomicAdd(&hist[c], 1u);
}

// ---------------- exclusive prefix over 4096 cells (1 block) ----------------
__global__ __launch_bounds__(1024) void prefix_kernel(const unsigned* __restrict__ hist,
                                                      unsigned* __restrict__ cellstart,
                                                      unsigned* __restrict__ cellptr) {
    __shared__ unsigned sbuf[1024];
    int tid = threadIdx.x;
    uint4 v = ((const uint4*)hist)[tid];
    unsigned mysum = v.x + v.y + v.z + v.w;
    sbuf[tid] = mysum;
    __syncthreads();
    for (int off = 1; off < 1024; off <<= 1) {
        unsigned add = (tid >= off) ? sbuf[tid - off] : 0u;
        __syncthreads();
        sbuf[tid] += add;
        __syncthreads();
    }
    unsigned excl = sbuf[tid] - mysum;
    unsigned p0 = excl, p1 = p0 + v.x, p2 = p1 + v.y, p3 = p2 + v.z;
    cellstart[4*tid+0] = p0; cellstart[4*tid+1] = p1;
    cellstart[4*tid+2] = p2; cellstart[4*tid+3] = p3;
    cellptr[4*tid+0] = p0; cellptr[4*tid+1] = p1;
    cellptr[4*tid+2] = p2; cellptr[4*tid+3] = p3;
    if (tid == 1023) cellstart[4096] = p3 + v.w;
}

// ---------------- scatter into cell-sorted order (+ relabeled geo/probs) ----------------
__global__ void scatter_kernel(const float4* __restrict__ bq, const int* __restrict__ cellid,
                               const float* __restrict__ geo, const float* __restrict__ probs,
                               unsigned* __restrict__ cellptr, float4* __restrict__ bqs,
                               int* __restrict__ oid, int* __restrict__ csort,
                               float* __restrict__ geo_s, float* __restrict__ probs_s) {
    int t = blockIdx.x * 256 + threadIdx.x;
    if (t >= T_TRI) return;
    int c = cellid[t];
    unsigned p = atomicAdd(&cellptr[c], 1u);
    bqs[p] = bq[t];
    oid[p]  = t;
    csort[p] = c;
    const float4* g4 = (const float4*)geo;
    float4* g4s = (float4*)geo_s;
    g4s[(size_t)p*3+0] = g4[(size_t)t*3+0];
    g4s[(size_t)p*3+1] = g4[(size_t)t*3+1];
    g4s[(size_t)p*3+2] = g4[(size_t)t*3+2];
    probs_s[p] = probs[t];
}

// ---------------- grid KNN — R20 algorithm, 128-thread blocks + hoisted w=1 loads ----------------
// R21 lesson: block-order remap was neutral (reverted) — the occupancy gap is
// scheduling GRANULARITY: 5000 4-wave blocks = 2.44 generations/CU, and each
// block retires at its slowest wave. 128-thread blocks (10000 x 2 waves) give
// 4x finer backfill. The w=1 box's cellstart loads (~200cy, independent of
// the seed sort) are hoisted ABOVE the home bitonic so they overlap the sort
// chain; the theta-dependent bound check still runs after the seed.
// Candidate set, drain logic, pruning, stop bound: byte-identical to R20.
__global__ __launch_bounds__(128) void knn_grid_kernel(const float4* __restrict__ bqs,
        const int* __restrict__ oid, const int* __restrict__ csort,
        const unsigned* __restrict__ cellstart, const unsigned* __restrict__ mm,
        int* __restrict__ nbr) {
    int wave = threadIdx.x >> 6, lane = threadIdx.x & 63;
    int r = blockIdx.x * 2 + wave;
    float4 q = bqs[r];
    int myc = csort[r];
    int cx = (myc>>8)&15, cy = (myc>>4)&15, cz = myc&15;
    float mnx = decf(mm[0]), mny = decf(mm[1]), mnz = decf(mm[2]);
    float hx = (decf(mm[3]) - mnx) * (1.f/16.f);
    float hy = (decf(mm[4]) - mny) * (1.f/16.f);
    float hz = (decf(mm[5]) - mnz) * (1.f/16.f);
    float hmin = fminf(hx, fminf(hy, hz));

    float rd = INFINITY;
    int   ri = 0x7FF00000 | lane;     // distinct sentinels (orig-idx key)
    int   rk = lane;                  // sorted-idx payload
    float th = INFINITY;
    int   mi = 0x7FFFFFFF;

#define SCAN_RANGE(RS, RE)                                                          \
    for (unsigned base = (RS); base < (RE); base += 64u) {                          \
        unsigned k = base + (unsigned)lane;                                         \
        bool kv = (k < (RE));                                                       \
        float4 c4 = kv ? bqs[k] : make_float4(INFINITY,INFINITY,INFINITY,INFINITY); \
        int ov = kv ? oid[k] : 0x7FFFFFFF;                                          \
        float dot = fmaf(q.z, c4.z, fmaf(q.y, c4.y, q.x*c4.x));                     \
        float d = (q.w + c4.w) - 2.0f*dot;                                          \
        unsigned long long bal = __ballot(kv && (d <= th));                         \
        while (bal) {                                                               \
            int src = __ffsll(bal) - 1; bal &= bal - 1;                             \
            float dc = readlane_f(d, src);                                          \
            int   jc = __builtin_amdgcn_readlane(ov, src);                          \
            int   kc = (int)base + src;                                             \
            if ((dc < th) || (dc == th && jc < mi)) {                               \
                bool less = (rd < dc) || (rd == dc && ri < jc);                     \
                int pos = __popcll(__ballot(less) & 0x1FFFFFull);                   \
                float sd = __shfl_up(rd, 1);                                        \
                int   si = __shfl_up(ri, 1);                                        \
                int   sk = __shfl_up(rk, 1);                                        \
                if (lane < 21) {                                                    \
                    if (lane == pos)      { rd = dc; ri = jc; rk = kc; }            \
                    else if (lane > pos)  { rd = sd; ri = si; rk = sk; }            \
                }                                                                   \
                th = readlane_f(rd, 20);                                            \
                mi = __builtin_amdgcn_readlane(ri, 20);                             \
            }                                                                       \
        }                                                                           \
    }

#define CELL_BOUND_OK(EX, EY, EZ)                                                   \
    ({  float cl0 = fmaf((float)(EX), hx, mnx);                                     \
        float cm0 = fmaf((float)(EY), hy, mny);                                     \
        float cn0 = fmaf((float)(EZ), hz, mnz);                                     \
        float ddx = fmaxf(fmaxf(cl0 - q.x, q.x - (cl0 + hx)), 0.f);                 \
        float ddy = fmaxf(fmaxf(cm0 - q.y, q.y - (cm0 + hy)), 0.f);                 \
        float ddz = fmaxf(fmaxf(cn0 - q.z, q.z - (cn0 + hz)), 0.f);                 \
        float bnd = fmaf(ddx, ddx, fmaf(ddy, ddy, ddz*ddz));                        \
        (bnd <= th + 1e-3f); })

    // ---- hoisted w=1 box cell ranges (independent of the seed sort; the
    //      ~200cy cellstart loads overlap the bitonic chain below) ----
    int w1ex, w1ey, w1ez;
    bool w1geom;
    unsigned w1cs = 0u, w1ce = 0u;
    {
        int i = lane;
        w1geom = (i < 27) && (i != 13);
        int ii = (i < 27) ? i : 0;
        int dz = ii % 3 - 1, dy = (ii / 3) % 3 - 1, dx = ii / 9 - 1;
        w1ex = cx + dx; w1ey = cy + dy; w1ez = cz + dz;
        w1geom = w1geom && w1ex >= 0 && w1ex < 16 && w1ey >= 0 && w1ey < 16
                        && w1ez >= 0 && w1ez < 16;
        int cell = (w1ex<<8) | (w1ey<<4) | w1ez;
        if (w1geom) { w1cs = cellstart[cell]; w1ce = cellstart[cell+1]; }
    }

    // ---- home cell: first batch via bitonic sort (warm-up elimination) ----
    {
        unsigned hs = cellstart[myc], he = cellstart[myc + 1];
        unsigned k64 = hs + (unsigned)lane;
        bool kv = (k64 < he);
        float4 c4 = kv ? bqs[k64] : make_float4(INFINITY,INFINITY,INFINITY,INFINITY);
        float dot = fmaf(q.z, c4.z, fmaf(q.y, c4.y, q.x*c4.x));
        float d = (q.w + c4.w) - 2.0f*dot;
        int   jx = kv ? oid[k64] : (0x7FF00000 | lane);
        int   kc = kv ? (int)k64 : 0;
        if (!kv) d = INFINITY;          // kill NaN/INF garbage: sort needs clean keys
#pragma unroll
        for (int kk = 2; kk <= 64; kk <<= 1) {
#pragma unroll
            for (int jj = kk >> 1; jj >= 1; jj >>= 1) {
                float od = __shfl_xor(d, jj);
                int   oj = __shfl_xor(jx, jj);
                int   ok = __shfl_xor(kc, jj);
                bool up    = ((lane & kk) == 0);
                bool lower = ((lane & jj) == 0);
                bool less  = (d < od) || (d == od && jx < oj);
                bool keep  = ((lower == up) ? less : !less);
                d = keep ? d : od; jx = keep ? jx : oj; kc = keep ? kc : ok;
            }
        }
        rd = d; ri = jx; rk = kc;       // lane l = rank-l (junk for l>20, harmless)
        th = readlane_f(rd, 20);
        mi = __builtin_amdgcn_readlane(ri, 20);
        if (hs + 64u < he) { SCAN_RANGE(hs + 64u, he) }
    }

    for (int w = 1; w <= 15; ++w) {
        if (w == 1) {
            bool val = w1geom && (w1cs < w1ce);
            if (val) val = CELL_BOUND_OK(w1ex, w1ey, w1ez);
            unsigned long long cm = __ballot(val);
            while (cm) {
                int cl = __ffsll(cm) - 1; cm &= cm - 1;
                unsigned s0 = (unsigned)__builtin_amdgcn_readlane((int)w1cs, cl);
                unsigned e0 = (unsigned)__builtin_amdgcn_readlane((int)w1ce, cl);
                SCAN_RANGE(s0, e0)
            }
        } else {
            int W = 2*w + 1, W2 = W*W, tot = W*W2;
            for (int b0 = 0; b0 < tot; b0 += 64) {
                int i = b0 + lane;
                bool val = (i < tot);
                int ii = val ? i : 0;
                int dz = ii % W - w, dy = (ii / W) % W - w, dx = ii / W2 - w;
                int cheb = max(abs(dx), max(abs(dy), abs(dz)));
                val = val && (cheb == w);
                int ex = cx + dx, ey = cy + dy, ez = cz + dz;
                val = val && ex >= 0 && ex < 16 && ey >= 0 && ey < 16 && ez >= 0 && ez < 16;
                int cell = (ex<<8) | (ey<<4) | ez;
                unsigned cs = 0u, ce = 0u;
                if (val) { cs = cellstart[cell]; ce = cellstart[cell+1]; }
                val = val && (cs < ce);
                if (val) val = CELL_BOUND_OK(ex, ey, ez);
                unsigned long long cm = __ballot(val);
                while (cm) {
                    int cl = __ffsll(cm) - 1; cm &= cm - 1;
                    unsigned s0 = (unsigned)__builtin_amdgcn_readlane((int)cs, cl);
                    unsigned e0 = (unsigned)__builtin_amdgcn_readlane((int)ce, cl);
                    SCAN_RANGE(s0, e0)
                }
            }
        }
        bool covered = (cx-w <= 0) && (cx+w >= 15) && (cy-w <= 0) && (cy+w >= 15)
                    && (cz-w <= 0) && (cz+w >= 15);
        if (covered) break;
        float bd = (float)w * hmin - 1e-3f;
        if (bd > 0.f && th < bd*bd) break;
    }
#undef CELL_BOUND_OK
#undef SCAN_RANGE
    if (lane >= 1 && lane < 21) nbr[r*KNN_K + lane - 1] = rk;
}

// ---------------- layer-0 Z ----------------
__global__ void y0_kernel(const float* __restrict__ ps, const float* __restrict__ rs,
                          const float* __restrict__ WA0, const float* __restrict__ geo_s,
                          float* __restrict__ Z) {
    int bid = xcd_swz(blockIdx.x, gridDim.x);
    int tid = bid * 256 + threadIdx.x;   // over T*H
    int t = tid >> 7, f = tid & 127;
    float acc = ps[t] * rs[f];
#pragma unroll
    for (int c = 0; c < 9; ++c)
        acc = fmaf(WA0[c*128 + f], geo_s[(size_t)t*12 + c], acc);
    Z[tid] = acc;
}

// ---------------- mid-layer fused: 8 rows / 512-thread block ----------------
__global__ __launch_bounds__(512) void ef_mid_kernel(const float* __restrict__ Z,
                            const int* __restrict__ nbr, const float* __restrict__ b1,
                            const float* __restrict__ MTg, const float* __restrict__ v,
                            const float* __restrict__ WAn, const float* __restrict__ geo_s,
                            float* __restrict__ Znext) {
    __shared__ float Srow[8][128];
    int wave = threadIdx.x >> 6, lane = threadIdx.x & 63;
    int t0b = xcd_swz(blockIdx.x, gridDim.x) * 8;
    {
        int t = t0b + wave;
        float zsLo = Z[(size_t)t*H + lane]      + b1[lane];
        float zsHi = Z[(size_t)t*H + 64 + lane] + b1[64 + lane];
        float accLo = 0.f, accHi = 0.f;
#pragma unroll
        for (int e = 0; e < KNN_K; ++e) {
            int tg = nbr[t*KNN_K + e];
            accLo += fmaxf(zsLo - Z[(size_t)tg*H + lane],      0.f);
            accHi += fmaxf(zsHi - Z[(size_t)tg*H + 64 + lane], 0.f);
        }
        Srow[wave][lane]    = accLo;
        Srow[wave][64+lane] = accHi;
    }
    __syncthreads();
    int f = threadIdx.x & 127, grp = threadIdx.x >> 7;   // 4 groups x 2 rows
    float a0 = v[f], a1 = v[f];
    const int r0_ = grp * 2;
#pragma unroll
    for (int c4 = 0; c4 < 32; ++c4) {
        float4 w = *(const float4*)&MTg[c4*512 + f*4];
        float4 v0 = ((const float4*)Srow[r0_+0])[c4];
        float4 v1 = ((const float4*)Srow[r0_+1])[c4];
        a0 = fmaf(w.x, v0.x, a0); a0 = fmaf(w.y, v0.y, a0);
        a0 = fmaf(w.z, v0.z, a0); a0 = fmaf(w.w, v0.w, a0);
        a1 = fmaf(w.x, v1.x, a1); a1 = fmaf(w.y, v1.y, a1);
        a1 = fmaf(w.z, v1.z, a1); a1 = fmaf(w.w, v1.w, a1);
    }
#pragma unroll
    for (int c = 0; c < 9; ++c) {
        float w = WAn[c*128 + f];
        a0 = fmaf(w, geo_s[(size_t)(t0b + r0_ + 0)*12 + c], a0);
        a1 = fmaf(w, geo_s[(size_t)(t0b + r0_ + 1)*12 + c], a1);
    }
    Znext[(size_t)(t0b+r0_+0)*H + f] = a0;
    Znext[(size_t)(t0b+r0_+1)*H + f] = a1;
}

// ---------------- last-layer fused: edge -> dot(S, wf2) + cst -> sigmoid ----------------
__global__ __launch_bounds__(256) void ef_head_kernel(const float* __restrict__ Z,
                            const int* __restrict__ nbr, const float* __restrict__ b1,
                            const float* __restrict__ WV, float* __restrict__ out,
                            const int* __restrict__ oid) {
    int wave = threadIdx.x >> 6, lane = threadIdx.x & 63;
    int t = xcd_swz(blockIdx.x, gridDim.x) * 4 + wave;
    float zsLo = Z[(size_t)t*H + lane]      + b1[lane];
    float zsHi = Z[(size_t)t*H + 64 + lane] + b1[64 + lane];
    float accLo = 0.f, accHi = 0.f;
#pragma unroll
    for (int e = 0; e < KNN_K; ++e) {
        int tg = nbr[t*KNN_K + e];
        accLo += fmaxf(zsLo - Z[(size_t)tg*H + lane],      0.f);
        accHi += fmaxf(zsHi - Z[(size_t)tg*H + 64 + lane], 0.f);
    }
    float p = fmaf(accLo, WV[256 + lane], accHi * WV[256 + 64 + lane]);
#pragma unroll
    for (int off = 32; off >= 1; off >>= 1) p += __shfl_xor(p, off);
    if (lane == 0) {
        float z = p + WV[384];
        out[oid[t]] = 1.0f / (1.0f + expf(-z));
    }
}

extern "C" void kernel_launch(void* const* d_in, const int* in_sizes, int n_in,
                              void* d_out, int out_size, void* d_ws, size_t ws_size,
                              hipStream_t stream) {
    (void)in_sizes; (void)n_in; (void)out_size; (void)ws_size;
    const float* pts   = (const float*)d_in[0];
    const int*   tris  = (const int*)d_in[1];
    const float* probs = (const float*)d_in[2];
    const float* W1[3] = {(const float*)d_in[3],  (const float*)d_in[7],  (const float*)d_in[11]};
    const float* b1[3] = {(const float*)d_in[4],  (const float*)d_in[8],  (const float*)d_in[12]};
    const float* W2[3] = {(const float*)d_in[5],  (const float*)d_in[9],  (const float*)d_in[13]};
    const float* b2[3] = {(const float*)d_in[6],  (const float*)d_in[10], (const float*)d_in[14]};
    const float* Wf = (const float*)d_in[15];
    const float* bf = (const float*)d_in[16];
    float* out = (float*)d_out;

    char* ws = (char*)d_ws;
    float*    geo  = (float*)(ws + WS_GEO);
    float4*   bq   = (float4*)(ws + WS_BQ);
    int*      nbr  = (int*)(ws + WS_NBR);
    float*    rs   = (float*)(ws + WS_RS);
    float*    MTg  = (float*)(ws + WS_MT);
    float*    WV   = (float*)(ws + WS_WV);
    unsigned* mm   = (unsigned*)(ws + WS_MM);
    unsigned* cst  = (unsigned*)(ws + WS_CSTART);
    unsigned* cptr = (unsigned*)(ws + WS_CPTR);
    unsigned* hist = (unsigned*)(ws + WS_HIST);
    int*      cid  = (int*)(ws + WS_CID);
    int*      cso  = (int*)(ws + WS_CSORT);
    int*      oid  = (int*)(ws + WS_OID);
    float4*   bqs  = (float4*)(ws + WS_BQS);
    float*    WA   = (float*)(ws + WS_WA);
    float*    ps   = (float*)(ws + WS_PS);
    float*    geos = (float*)(ws + WS_GEOS);
    float*    Za   = (float*)(ws + WS_ZA);
    float*    Zb   = (float*)(ws + WS_ZB);

    setup_kernel<<<dim3(130,2), 128, 0, stream>>>(W1[0], W1[1], W1[2], W2[0], W2[1],
                                                  b2[0], b2[1], b2[2], W2[2], Wf, bf,
                                                  hist, mm, rs, WA, WV, MTg);
    geom_kernel<<<(T_TRI+255)/256, 256, 0, stream>>>(pts, tris, geo, bq, mm);
    cellhist_kernel<<<(T_TRI+255)/256, 256, 0, stream>>>(bq, mm, cid, hist);
    prefix_kernel<<<1, 1024, 0, stream>>>(hist, cst, cptr);
    scatter_kernel<<<(T_TRI+255)/256, 256, 0, stream>>>(bq, cid, geo, probs, cptr, bqs, oid, cso, geos, ps);
    knn_grid_kernel<<<T_TRI/2, 128, 0, stream>>>(bqs, oid, cso, cst, mm, nbr);
    y0_kernel<<<(T_TRI*H)/256, 256, 0, stream>>>(ps, rs, WA, geos, Za);
    ef_mid_kernel<<<T_TRI/8, 512, 0, stream>>>(Za, nbr, b1[0], MTg,         WV,       WA + 1*1152, geos, Zb);
    ef_mid_kernel<<<T_TRI/8, 512, 0, stream>>>(Zb, nbr, b1[1], MTg + 16384, WV + 128, WA + 2*1152, geos, Za);
    ef_head_kernel<<<T_TRI/4, 256, 0, stream>>>(Za, nbr, b1[2], WV, out, oid);
}